// Round 5
// baseline (108.007 us; speedup 1.0000x reference)
//
#include <hip/hip_runtime.h>
#include <math.h>

#define H 256
#define E_DIM 300
#define LEN 128
#define S_STEPS 127
#define AMB 32
#define EPSV 1e-8f

typedef __attribute__((ext_vector_type(8))) short short8v;   // 8 bf16 (4 VGPRs)
typedef __attribute__((ext_vector_type(4))) float f32x4;

// ws layout (float offsets)
#define UB_OFF    0        // U bf16 [1280][512]
#define WB_OFF    327680   // W bf16 [768][320]
#define W1B_OFF   450560   // w1 bf16 [1024][512]
#define UNORM_OFF 712704   // 1 (pad 256)
#define EMBB_OFF  712960   // emb bf16 [4096][320]
#define CL_OFF    1040640  // c_leaf f32 [4096][256]
#define HLB_OFF   2089216  // h_leaf bf16 [4096][256]
#define H2_OFF    2351360  // h2 f32 [2048][256]
// end 2875648 floats ~ 11.5 MB

__device__ __forceinline__ float sigf(float x) { return 1.0f / (1.0f + expf(-x)); }
__device__ __forceinline__ unsigned short f2bf(float f) {
    unsigned int u = __float_as_uint(f);
    return (unsigned short)((u + 0x7fffu + ((u >> 16) & 1u)) >> 16);
}
__device__ __forceinline__ float bf_lo(unsigned int u) { return __uint_as_float(u << 16); }
__device__ __forceinline__ float bf_hi(unsigned int u) { return __uint_as_float(u & 0xffff0000u); }

// ---- K0: W bf16 convert + emb gather + ||u|| ----
__global__ __launch_bounds__(256) void k_prep(
    const float* __restrict__ W, const float* __restrict__ eu,
    const float* __restrict__ wemb,
    const int* __restrict__ sent1, const int* __restrict__ ops1,
    const int* __restrict__ sent2, const int* __restrict__ ops2,
    float* __restrict__ ws) {
    __shared__ float upart[4];
    if (blockIdx.x == 0) {
        int t = threadIdx.x;
        float v = eu[t];
        v *= v;
#pragma unroll
        for (int off = 32; off >= 1; off >>= 1) v += __shfl_xor(v, off);
        if ((t & 63) == 0) upart[t >> 6] = v;
        __syncthreads();
        if (t == 0) ws[UNORM_OFF] = sqrtf(upart[0] + upart[1] + upart[2] + upart[3]);
    }
    unsigned short* __restrict__ wb   = (unsigned short*)(ws + WB_OFF);
    unsigned short* __restrict__ embb = (unsigned short*)(ws + EMBB_OFF);
    const int NW = 768 * 320;       // 245760
    const int NG = 4096 * 80;       // 327680 gather units (4 floats each)
    const int total = NW + NG;
    for (int idx = blockIdx.x * 256 + threadIdx.x; idx < total; idx += gridDim.x * 256) {
        if (idx < NW) {
            int r = idx / 320, k = idx - r * 320;
            int g = r >> 8;
            int forig = (r & 255) + (g == 0 ? 0 : (g == 1 ? 768 : 1024));
            wb[idx] = (k < E_DIM) ? f2bf(W[forig * E_DIM + k]) : (unsigned short)0;
        } else {
            int j = idx - NW;
            int slot = j / 80;
            int e0 = (j - slot * 80) * 4;
            int sent = slot >> 11, b = (slot >> 6) & 31, a = (slot >> 1) & 31, side = slot & 1;
            const int* __restrict__ ops   = sent ? ops2  : ops1;
            const int* __restrict__ sents = sent ? sent2 : sent1;
            int op  = ops[((b * S_STEPS + 126) * AMB + a) * 2 + side];
            int tok = sents[b * LEN + op];
            unsigned short o0 = 0, o1 = 0, o2 = 0, o3 = 0;
            if (e0 < E_DIM) {
                float4 v = *reinterpret_cast<const float4*>(&wemb[tok * E_DIM + e0]);
                o0 = f2bf(v.x); o1 = f2bf(v.y); o2 = f2bf(v.z); o3 = f2bf(v.w);
            }
            unsigned short* p = &embb[slot * 320 + e0];
            p[0] = o0; p[1] = o1; p[2] = o2; p[3] = o3;
        }
    }
}

// ---- K1: leaf gates MFMA [4096]x[768]x[320] (16-row tiles, 4096 waves)
//      + U bf16 convert in blocks [1024, 1184) ----
__global__ __launch_bounds__(256) void k_leaf(
    const float* __restrict__ ws_ro, float* __restrict__ ws,
    const float* __restrict__ bvec, const float* __restrict__ U) {
    const int t = threadIdx.x;
    if (blockIdx.x >= 1024) {                 // U convert: 1280x512 = 163840 float4s
        const float4* __restrict__ Uf = (const float4*)U;
        ushort4* __restrict__ ub4 = (ushort4*)(ws + UB_OFF);
        for (int i = (blockIdx.x - 1024) * 256 + t; i < 163840; i += 160 * 256) {
            float4 v = Uf[i];
            ushort4 o; o.x = f2bf(v.x); o.y = f2bf(v.y); o.z = f2bf(v.z); o.w = f2bf(v.w);
            ub4[i] = o;
        }
        return;
    }
    const int l = t & 63;
    const int gw = blockIdx.x * 4 + (t >> 6);
    const int m0 = (gw & 255) * 16;
    const int c0 = (gw >> 8) * 16;
    const int lr = l & 15, lk = (l >> 4) * 8;

    const unsigned short* __restrict__ embb = (const unsigned short*)(ws_ro + EMBB_OFF);
    const unsigned short* __restrict__ wb   = (const unsigned short*)(ws_ro + WB_OFF);

    f32x4 acc[3];
#pragma unroll
    for (int g = 0; g < 3; g++) acc[g] = (f32x4)0.0f;

    const unsigned short* arow = embb + (m0 + lr) * 320 + lk;
    const unsigned short* brow = wb + (c0 + lr) * 320 + lk;
#pragma unroll
    for (int kt = 0; kt < 10; kt++) {
        short8v a0 = *reinterpret_cast<const short8v*>(arow + kt * 32);
#pragma unroll
        for (int g = 0; g < 3; g++) {
            short8v bg = *reinterpret_cast<const short8v*>(brow + (g * 256) * 320 + kt * 32);
            acc[g] = __builtin_amdgcn_mfma_f32_16x16x32_bf16(a0, bg, acc[g], 0, 0, 0);
        }
    }

    const int col = c0 + lr;
    const float b0 = bvec[col], b3 = bvec[col + 768], b4 = bvec[col + 1024];
    float* __restrict__ cl = ws + CL_OFF;
    unsigned short* __restrict__ hlb = (unsigned short*)(ws + HLB_OFF);
#pragma unroll
    for (int i = 0; i < 4; i++) {
        int row = m0 + (l >> 4) * 4 + i;
        float gi = sigf(acc[0][i] + b0);
        float go = sigf(acc[1][i] + b3);
        float gu = tanhf(acc[2][i] + b4);
        float c = gi * gu;
        cl[row * 256 + col] = c;
        hlb[row * 256 + col] = f2bf(go * tanhf(c));
    }
}

// ---- K2: combine gates MFMA [2048]x[1280]x[512] (16-row tiles, 2048 waves)
//      + w1 bf16 convert in blocks [512, 640) ----
__global__ __launch_bounds__(256) void k_comb(
    const float* __restrict__ ws_ro, float* __restrict__ ws,
    const float* __restrict__ bvec, const float* __restrict__ w1) {
    const int t = threadIdx.x;
    if (blockIdx.x >= 512) {                  // w1 convert: 1024x512 = 131072 float4s
        const float4* __restrict__ w1f = (const float4*)w1;
        ushort4* __restrict__ w1b4 = (ushort4*)(ws + W1B_OFF);
        for (int i = (blockIdx.x - 512) * 256 + t; i < 131072; i += 128 * 256) {
            float4 v = w1f[i];
            ushort4 o; o.x = f2bf(v.x); o.y = f2bf(v.y); o.z = f2bf(v.z); o.w = f2bf(v.w);
            w1b4[i] = o;
        }
        return;
    }
    const int l = t & 63;
    const int gw = blockIdx.x * 4 + (t >> 6);
    const int m0 = (gw & 127) * 16;           // pair tile
    const int c0 = (gw >> 7) * 16;
    const int lr = l & 15, lk = (l >> 4) * 8;

    const unsigned short* __restrict__ hlb = (const unsigned short*)(ws_ro + HLB_OFF);
    const unsigned short* __restrict__ ub  = (const unsigned short*)(ws_ro + UB_OFF);

    f32x4 acc[5];
#pragma unroll
    for (int g = 0; g < 5; g++) acc[g] = (f32x4)0.0f;

    const unsigned short* arow = hlb + (m0 + lr) * 512 + lk;   // [2048][512] view
    const unsigned short* brow = ub + (c0 + lr) * 512 + lk;
#pragma unroll
    for (int kt = 0; kt < 16; kt++) {
        short8v a0 = *reinterpret_cast<const short8v*>(arow + kt * 32);
#pragma unroll
        for (int g = 0; g < 5; g++) {
            short8v bg = *reinterpret_cast<const short8v*>(brow + (g * 256) * 512 + kt * 32);
            acc[g] = __builtin_amdgcn_mfma_f32_16x16x32_bf16(a0, bg, acc[g], 0, 0, 0);
        }
    }

    const int col = c0 + lr;
    float bb[5];
#pragma unroll
    for (int g = 0; g < 5; g++) bb[g] = bvec[col + g * 256];
    const float* __restrict__ cl = ws_ro + CL_OFF;
    float* __restrict__ h2 = ws + H2_OFF;
#pragma unroll
    for (int i = 0; i < 4; i++) {
        int p = m0 + (l >> 4) * 4 + i;
        float gi  = sigf(acc[0][i] + bb[0]);
        float gfL = sigf(acc[1][i] + bb[1]);
        float gfR = sigf(acc[2][i] + bb[2]);
        float go  = sigf(acc[3][i] + bb[3]);
        float gu  = tanhf(acc[4][i] + bb[4]);
        float c = gfL * cl[(2 * p) * 256 + col] + gfR * cl[(2 * p + 1) * 256 + col] + gi * gu;
        h2[p * 256 + col] = go * tanhf(c);
    }
}

// ---- K3: fused tail — energies+softmax+weighted-sum (both sentences), MLP, output ----
// 32 blocks (one per batch row b), 256 threads.
__global__ __launch_bounds__(256) void k_tail(
    const float* __restrict__ ws_ro, const float* __restrict__ eu,
    const float* __restrict__ b1, const float* __restrict__ w2,
    const float* __restrict__ b2, float* __restrict__ out) {
    const int b = blockIdx.x, t = threadIdx.x;
    const int w = t >> 6, lane = t & 63;
    __shared__ float e_s[32], s_s[32];
    __shared__ __align__(16) float conc[512];
    __shared__ float red[12];
    const float unorm = ws_ro[UNORM_OFF];
    const float* __restrict__ h2 = ws_ro + H2_OFF;

    for (int s = 0; s < 2; s++) {
        const int gb = s * 32 + b;
        for (int ai = 0; ai < 8; ai++) {
            int a = w * 8 + ai;
            const float* row = h2 + (gb * 32 + a) * 256;
            float num = 0.0f, den = 0.0f;
#pragma unroll
            for (int q = 0; q < 4; q++) {
                float v = row[lane + q * 64];
                num += v * eu[lane + q * 64];
                den += v * v;
            }
#pragma unroll
            for (int off = 32; off >= 1; off >>= 1) {
                num += __shfl_xor(num, off);
                den += __shfl_xor(den, off);
            }
            if (lane == 0) e_s[a] = num / fmaxf(sqrtf(den) * unorm, EPSV);
        }
        __syncthreads();
        if (t < 64) {
            float e = (t < 32) ? e_s[t] : -1e30f;
            float m = e;
#pragma unroll
            for (int off = 32; off >= 1; off >>= 1) m = fmaxf(m, __shfl_xor(m, off));
            float p = (t < 32) ? expf(e - m) : 0.0f;
            float sum = p;
#pragma unroll
            for (int off = 32; off >= 1; off >>= 1) sum += __shfl_xor(sum, off);
            if (t < 32) s_s[t] = p / sum;
        }
        __syncthreads();
        float acc = 0.0f;
        for (int a = 0; a < 32; a++)
            acc += s_s[a] * h2[(gb * 32 + a) * 256 + t];
        conc[s * 256 + t] = acc;
        __syncthreads();
    }

    // MLP: each thread owns units t, t+256, t+512, t+768 (full K=512)
    const unsigned short* __restrict__ w1b = (const unsigned short*)(ws_ro + W1B_OFF);
    float p0 = 0.0f, p1 = 0.0f, p2 = 0.0f;
#pragma unroll
    for (int k = 0; k < 4; k++) {
        const int m = t + (k << 8);
        float a = b1[m];
        const uint4* __restrict__ wp = reinterpret_cast<const uint4*>(w1b + m * 512);
        for (int e8 = 0; e8 < 64; e8++) {
            uint4 u = wp[e8];
            float4 ca = *reinterpret_cast<const float4*>(&conc[e8 * 8]);
            float4 cb = *reinterpret_cast<const float4*>(&conc[e8 * 8 + 4]);
            a = fmaf(bf_lo(u.x), ca.x, a); a = fmaf(bf_hi(u.x), ca.y, a);
            a = fmaf(bf_lo(u.y), ca.z, a); a = fmaf(bf_hi(u.y), ca.w, a);
            a = fmaf(bf_lo(u.z), cb.x, a); a = fmaf(bf_hi(u.z), cb.y, a);
            a = fmaf(bf_lo(u.w), cb.z, a); a = fmaf(bf_hi(u.w), cb.w, a);
        }
        a = fmaxf(a, 0.0f);
        p0 = fmaf(a, w2[m], p0);
        p1 = fmaf(a, w2[1024 + m], p1);
        p2 = fmaf(a, w2[2048 + m], p2);
    }
#pragma unroll
    for (int off = 32; off >= 1; off >>= 1) {
        p0 += __shfl_xor(p0, off);
        p1 += __shfl_xor(p1, off);
        p2 += __shfl_xor(p2, off);
    }
    if (lane == 0) { red[w * 3 + 0] = p0; red[w * 3 + 1] = p1; red[w * 3 + 2] = p2; }
    __syncthreads();
    if (t == 0) {
        float l0 = red[0] + red[3] + red[6] + red[9]  + b2[0];
        float l1 = red[1] + red[4] + red[7] + red[10] + b2[1];
        float l2 = red[2] + red[5] + red[8] + red[11] + b2[2];
        float m = fmaxf(l0, fmaxf(l1, l2));
        float e0 = expf(l0 - m), e1 = expf(l1 - m), e2 = expf(l2 - m);
        float s = e0 + e1 + e2;
        out[b * 3 + 0] = e0 / s;
        out[b * 3 + 1] = e1 / s;
        out[b * 3 + 2] = e2 / s;
    }
}

extern "C" void kernel_launch(void* const* d_in, const int* in_sizes, int n_in,
                              void* d_out, int out_size, void* d_ws, size_t ws_size,
                              hipStream_t stream) {
    const float* W    = (const float*)d_in[0];
    const float* U    = (const float*)d_in[1];
    const float* bvec = (const float*)d_in[2];
    const float* eu   = (const float*)d_in[3];
    const float* wemb = (const float*)d_in[4];
    const float* w1   = (const float*)d_in[5];
    const float* b1   = (const float*)d_in[6];
    const float* w2   = (const float*)d_in[7];
    const float* b2   = (const float*)d_in[8];
    const int* s1 = (const int*)d_in[9];
    const int* o1 = (const int*)d_in[10];
    const int* s2 = (const int*)d_in[11];
    const int* o2 = (const int*)d_in[12];
    float* ws  = (float*)d_ws;
    float* out = (float*)d_out;

    hipLaunchKernelGGL(k_prep, dim3(1024), dim3(256), 0, stream,
                       W, eu, wemb, s1, o1, s2, o2, ws);
    hipLaunchKernelGGL(k_leaf, dim3(1184), dim3(256), 0, stream, ws, ws, bvec, U);
    hipLaunchKernelGGL(k_comb, dim3(640),  dim3(256), 0, stream, ws, ws, bvec, w1);
    hipLaunchKernelGGL(k_tail, dim3(32),   dim3(256), 0, stream,
                       ws, eu, b1, w2, b2, out);
}